// Round 6
// baseline (60.733 us; speedup 1.0000x reference)
//
#include <hip/hip_runtime.h>
#include <hip/hip_bf16.h>
#include <math.h>

#define B_    2
#define Q_    900
#define QPAD_ 912      // 57 * 16
#define MT_   57
#define CC_   91
#define T_    64
#define H_    128
#define W_    128
#define HW_   (H_*W_)
#define P_    1024
#define FLT_BIG 3.402823466e+38f

typedef short short8 __attribute__((ext_vector_type(8)));   // 8 bf16 (4 VGPRs)
typedef float f32x4  __attribute__((ext_vector_type(4)));

static __device__ __forceinline__ unsigned short f2bf(float v) {
    __hip_bfloat16 h = __float2bfloat16(v);   // RN
    return *reinterpret_cast<unsigned short*>(&h);
}

// ---------------- k0: spatial sort of points + tap metadata (1 block) ----------------
// Output arrays are indexed by SORTED SLOT; all downstream P-sums are permutation-invariant.
__global__ __launch_bounds__(256) void k0_meta(
    const float* __restrict__ pc,          // [P,2]
    int4*  __restrict__ offs,              // [P] bilinear tap offsets (slot order)
    float4* __restrict__ wts,              // [P] bilinear tap weights (slot order)
    int*   __restrict__ nearm,             // [P] nearest idx or -1 (slot order)
    float* __restrict__ bmax)              // [B] zeroed here every call
{
    __shared__ int keys[P_];
    const int tid = threadIdx.x;
    if (tid < B_) bmax[tid] = 0.f;

    #pragma unroll
    for (int k = 0; k < 4; ++k) {
        int p = tid*4 + k;
        float px = pc[2*p], py = pc[2*p+1];
        float xf = rintf(px * (float)W_ - 0.5f);
        float yf = rintf(py * (float)H_ - 0.5f);
        int xc = (int)fminf(fmaxf(xf, 0.f), (float)(W_-1));
        int yc = (int)fminf(fmaxf(yf, 0.f), (float)(H_-1));
        keys[p] = ((yc*W_ + xc) << 10) | p;   // raster-order key, stable (unique p)
    }
    __syncthreads();

    // bitonic sort ascending (pairs disjoint per pass -> race-free)
    for (int kk = 2; kk <= P_; kk <<= 1) {
        for (int j = kk >> 1; j > 0; j >>= 1) {
            #pragma unroll
            for (int t = 0; t < 4; ++t) {
                int i = tid + t*256;
                int l = i ^ j;
                if (l > i) {
                    int a = keys[i], b = keys[l];
                    bool up = ((i & kk) == 0);
                    if ((a > b) == up) { keys[i] = b; keys[l] = a; }
                }
            }
            __syncthreads();
        }
    }

    // emit metadata in slot order (recompute from pc[src])
    #pragma unroll
    for (int k = 0; k < 4; ++k) {
        int s = tid*4 + k;
        int src = keys[s] & 1023;
        float px = pc[2*src], py = pc[2*src+1];

        // nearest (grid_sample nearest, align_corners=False; rintf == jnp.round)
        float xf = rintf(px * (float)W_ - 0.5f);
        float yf = rintf(py * (float)H_ - 0.5f);
        bool nv = (xf >= 0.f) && (xf < (float)W_) && (yf >= 0.f) && (yf < (float)H_);
        int xc = (int)fminf(fmaxf(xf, 0.f), (float)(W_-1));
        int yc = (int)fminf(fmaxf(yf, 0.f), (float)(H_-1));
        nearm[s] = nv ? (yc*W_ + xc) : -1;

        // bilinear taps
        float x = px * (float)W_ - 0.5f;
        float y = py * (float)H_ - 0.5f;
        float x0f = floorf(x), y0f = floorf(y);
        float wx1 = x - x0f, wy1 = y - y0f;
        float wx0 = 1.f - wx1, wy0 = 1.f - wy1;
        int x0 = (int)x0f, y0 = (int)y0f;
        int   xs2[2] = {x0, x0+1}, ys2[2] = {y0, y0+1};
        float wxs[2] = {wx0, wx1}, wys[2] = {wy0, wy1};
        int o[4]; float ww[4];
        #pragma unroll
        for (int dy = 0; dy < 2; ++dy)
        #pragma unroll
        for (int dx = 0; dx < 2; ++dx) {
            int xi = xs2[dx], yi = ys2[dy];
            bool v = (xi >= 0) && (xi < W_) && (yi >= 0) && (yi < H_);
            int xcc = min(max(xi, 0), W_-1);
            int ycc = min(max(yi, 0), H_-1);
            o[dy*2+dx]  = ycc*W_ + xcc;
            ww[dy*2+dx] = v ? wys[dy]*wxs[dx] : 0.f;
        }
        offs[s] = make_int4(o[0], o[1], o[2], o[3]);
        wts[s]  = make_float4(ww[0], ww[1], ww[2], ww[3]);
    }
}

// ---------------- kS: merged sampler — blocks [0,B*T) target-nearest, [B*T, B*T+B*Q) pred-bilinear ----------------
__global__ __launch_bounds__(256) void kS_sample(
    const float* __restrict__ tgt_masks,   // [B,T,H,W]
    const float* __restrict__ pred_masks,  // [B,Q,H,W]
    const int4*  __restrict__ offs,
    const float4* __restrict__ wts,
    const int*   __restrict__ nearm,
    unsigned short* __restrict__ tgtPT,    // [B][T][P] bf16 (slot order)
    float* __restrict__ tsum,              // [B,T]
    unsigned short* __restrict__ xsbuf,    // [B][2][QPAD][P] bf16 (ch0 = x, ch1 = s)
    float* __restrict__ lneg,              // [B,Q]
    float* __restrict__ lsum)              // [B,Q]
{
    const int tid = threadIdx.x;
    const int wv = tid >> 6, lane = tid & 63;
    __shared__ float sSum[2][4];

    if (blockIdx.x < B_*T_) {
        // ---- target role ----
        const int bt = blockIdx.x;
        const float* __restrict__ img = tgt_masks + (size_t)bt * HW_;

        int4 ni = *(const int4*)(nearm + tid*4);
        float v0 = (ni.x >= 0) ? img[ni.x] : 0.f;
        float v1 = (ni.y >= 0) ? img[ni.y] : 0.f;
        float v2 = (ni.z >= 0) ? img[ni.z] : 0.f;
        float v3 = (ni.w >= 0) ? img[ni.w] : 0.f;
        *(ushort4*)(tgtPT + (size_t)bt*P_ + tid*4) =
            make_ushort4(f2bf(v0), f2bf(v1), f2bf(v2), f2bf(v3));

        float local = (v0 + v1) + (v2 + v3);
        #pragma unroll
        for (int off = 32; off; off >>= 1) local += __shfl_down(local, off);
        if (lane == 0) sSum[0][wv] = local;
        __syncthreads();
        if (tid == 0) tsum[bt] = (sSum[0][0]+sSum[0][1]) + (sSum[0][2]+sSum[0][3]);
    } else {
        // ---- pred role ----
        const int bq = blockIdx.x - B_*T_;
        const int b = bq / Q_, q = bq % Q_;
        const float* __restrict__ img = pred_masks + (size_t)bq * HW_;

        float xv[4];
        {
            float tap[4][4];
            int4  o4[4]; float4 w4[4];
            #pragma unroll
            for (int k = 0; k < 4; ++k) { o4[k] = offs[tid*4 + k]; w4[k] = wts[tid*4 + k]; }
            #pragma unroll
            for (int k = 0; k < 4; ++k) {
                tap[k][0] = img[o4[k].x]; tap[k][1] = img[o4[k].y];
                tap[k][2] = img[o4[k].z]; tap[k][3] = img[o4[k].w];
            }
            #pragma unroll
            for (int k = 0; k < 4; ++k)
                xv[k] = w4[k].x*tap[k][0] + w4[k].y*tap[k][1] + w4[k].z*tap[k][2] + w4[k].w*tap[k][3];
        }

        float ln = 0.f, ls = 0.f;
        unsigned short px[4], ps[4];
        #pragma unroll
        for (int k = 0; k < 4; ++k) {
            float x = xv[k];
            float e  = __expf(-fabsf(x));
            float sp = __logf(1.f + e) + fmaxf(x, 0.f);   // softplus(x)
            float r  = 1.f / (1.f + e);
            float s  = (x >= 0.f) ? r : e * r;            // sigmoid(x)
            ln += sp; ls += s;
            px[k] = f2bf(x); ps[k] = f2bf(s);
        }

        *(ushort4*)(xsbuf + ((size_t)(b*2+0)*QPAD_ + q)*P_ + tid*4) = make_ushort4(px[0],px[1],px[2],px[3]);
        *(ushort4*)(xsbuf + ((size_t)(b*2+1)*QPAD_ + q)*P_ + tid*4) = make_ushort4(ps[0],ps[1],ps[2],ps[3]);

        #pragma unroll
        for (int off = 32; off; off >>= 1) {
            ln += __shfl_down(ln, off);
            ls += __shfl_down(ls, off);
        }
        if (lane == 0) { sSum[0][wv] = ln; sSum[1][wv] = ls; }
        __syncthreads();
        if (tid == 0) {
            lneg[b*Q_ + q] = (sSum[0][0]+sSum[0][1]) + (sSum[0][2]+sSum[0][3]);
            lsum[b*Q_ + q] = (sSum[1][0]+sSum[1][1]) + (sSum[1][2]+sSum[1][3]);
        }
    }
}

// ---------------- k3: MFMA GEMM, K split across 4 waves + LDS reduce + fused epilogue + fused max ----------------
__global__ __launch_bounds__(256) void k3_gemm(
    const unsigned short* __restrict__ xsbuf,  // [B][2][QPAD][P] bf16
    const unsigned short* __restrict__ tgtPT,  // [B][T][P] bf16
    const float* __restrict__ lneg,            // [B,Q]
    const float* __restrict__ lsum,            // [B,Q]
    const float* __restrict__ tsum,            // [B,T]
    const float* __restrict__ pred_logits,     // [B,Q,CC]
    const float* __restrict__ pred_boxes,      // [B,Q,4]
    const float* __restrict__ tgt_boxes,       // [B,T,4]
    const int*   __restrict__ tgt_labels,      // [B,T]
    float* __restrict__ out,                   // [B,Q,T]
    float* __restrict__ bmax)                  // [B]
{
    __shared__ f32x4 sAcc[4][64][8];     // 32 KB

    const int bid = blockIdx.x;          // b*MT_ + mt
    const int b = bid / MT_, mt = bid % MT_;
    const int w = threadIdx.x >> 6, l = threadIdx.x & 63;
    const int ml = l & 15, kg = l >> 4;

    // wave w covers k in [w*256, (w+1)*256)
    const short* Ax = (const short*)xsbuf + ((size_t)(b*2+0)*QPAD_ + mt*16 + ml)*P_ + kg*8 + w*256;
    const short* As = (const short*)xsbuf + ((size_t)(b*2+1)*QPAD_ + mt*16 + ml)*P_ + kg*8 + w*256;
    const short* Bb = (const short*)tgtPT + ((size_t)(b*T_) + ml)*P_ + kg*8 + w*256;

    f32x4 accX[4] = {{0,0,0,0},{0,0,0,0},{0,0,0,0},{0,0,0,0}};
    f32x4 accS[4] = {{0,0,0,0},{0,0,0,0},{0,0,0,0},{0,0,0,0}};

    #pragma unroll
    for (int kt = 0; kt < 8; ++kt) {
        const int ko = kt * 32;
        short8 afx = *(const short8*)(Ax + ko);
        short8 afs = *(const short8*)(As + ko);
        #pragma unroll
        for (int nt = 0; nt < 4; ++nt) {
            short8 bf = *(const short8*)(Bb + (size_t)nt*16*P_ + ko);
            accX[nt] = __builtin_amdgcn_mfma_f32_16x16x32_bf16(afx, bf, accX[nt], 0, 0, 0);
            accS[nt] = __builtin_amdgcn_mfma_f32_16x16x32_bf16(afs, bf, accS[nt], 0, 0, 0);
        }
    }

    #pragma unroll
    for (int nt = 0; nt < 4; ++nt) {
        sAcc[w][l][nt*2+0] = accX[nt];
        sAcc[w][l][nt*2+1] = accS[nt];
    }
    __syncthreads();

    // wave w handles epilogue for nt = w (t = w*16 + ml)
    f32x4 aX = sAcc[0][l][w*2+0];
    f32x4 aS = sAcc[0][l][w*2+1];
    #pragma unroll
    for (int w2 = 1; w2 < 4; ++w2) {
        aX += sAcc[w2][l][w*2+0];
        aS += sAcc[w2][l][w*2+1];
    }

    const int t = w*16 + ml;
    const float tsu = tsum[b*T_ + t];
    const int   lab = tgt_labels[b*T_ + t];
    const float4 tbx = *(const float4*)(tgt_boxes + (size_t)(b*T_ + t)*4);
    float tx1 = tbx.x - 0.5f*tbx.z, ty1 = tbx.y - 0.5f*tbx.w;
    float tx2 = tbx.x + 0.5f*tbx.z, ty2 = tbx.y + 0.5f*tbx.w;
    float a2 = (tx2-tx1)*(ty2-ty1);

    float mloc = 0.f;   // per-thread max of where(finite, C, 0) candidates

    #pragma unroll
    for (int r = 0; r < 4; ++r) {
        int q = mt*16 + kg*4 + r;
        int qc = min(q, Q_-1);
        float ln  = lneg[b*Q_ + qc];
        float lsv = lsum[b*Q_ + qc];
        float4 pb = *(const float4*)(pred_boxes + (size_t)(b*Q_ + qc)*4);
        float lg = pred_logits[((size_t)(b*Q_ + qc))*CC_ + lab];

        float ce   = (ln - aX[r]) * (1.f/(float)P_);
        float dice = 1.f - (2.f*aS[r] + 1.f) / (lsv + tsu + 1.f);

        float e  = __expf(-fabsf(lg));
        float lp = log1pf(e);
        float sp_neg = lp + fmaxf(-lg, 0.f);
        float sp_pos = lp + fmaxf( lg, 0.f);
        float prob = 1.f / (1.f + __expf(-lg));
        float cclass = 0.25f*(1.f-prob)*(1.f-prob)*sp_neg - 0.75f*prob*prob*sp_pos;

        float cbbox = fabsf(pb.x-tbx.x) + fabsf(pb.y-tbx.y) + fabsf(pb.z-tbx.z) + fabsf(pb.w-tbx.w);
        float px1 = pb.x - 0.5f*pb.z, py1 = pb.y - 0.5f*pb.w;
        float px2 = pb.x + 0.5f*pb.z, py2 = pb.y + 0.5f*pb.w;
        float a1 = (px2-px1)*(py2-py1);
        float iw = fmaxf(fminf(px2,tx2) - fmaxf(px1,tx1), 0.f);
        float ih = fmaxf(fminf(py2,ty2) - fmaxf(py1,ty1), 0.f);
        float inter = iw*ih;
        float uni = a1 + a2 - inter;
        float iou = inter / uni;
        float cw = fmaxf(fmaxf(px2,tx2) - fminf(px1,tx1), 0.f);
        float ch = fmaxf(fmaxf(py2,ty2) - fminf(py1,ty1), 0.f);
        float ac = cw*ch;
        float giou = iou - (ac - uni)/ac;

        float cost = cbbox + cclass - giou + ce + dice;
        if (q < Q_) {
            out[((size_t)(b*Q_ + q))*T_ + t] = cost;
            float cand = (fabsf(cost) <= FLT_BIG) ? cost : 0.f;
            mloc = fmaxf(mloc, cand);
        }
    }

    // block-reduce max -> one atomic per block (bm >= 0: uint order == float order)
    #pragma unroll
    for (int off = 32; off; off >>= 1) mloc = fmaxf(mloc, __shfl_down(mloc, off));
    __shared__ float sm[4];
    if (l == 0) sm[w] = mloc;
    __syncthreads();
    if (threadIdx.x == 0) {
        float bm = fmaxf(fmaxf(sm[0], sm[1]), fmaxf(sm[2], sm[3]));
        atomicMax((unsigned int*)&bmax[b], __float_as_uint(bm));
    }
}

// ---------------- k5: replace non-finite with 2*max ----------------
__global__ __launch_bounds__(256) void k5_fix(float* __restrict__ out,
                                              const float* __restrict__ bmax)
{
    int i = blockIdx.x*256 + threadIdx.x;
    if (i >= B_*Q_*T_) return;
    float v = out[i];
    if (!(fabsf(v) <= FLT_BIG))
        out[i] = 2.f * bmax[i / (Q_*T_)];
}

extern "C" void kernel_launch(void* const* d_in, const int* in_sizes, int n_in,
                              void* d_out, int out_size, void* d_ws, size_t ws_size,
                              hipStream_t stream) {
    const float* pred_logits  = (const float*)d_in[0];
    const float* pred_boxes   = (const float*)d_in[1];
    const float* pred_masks   = (const float*)d_in[2];
    const float* tgt_boxes    = (const float*)d_in[3];
    const float* tgt_masks    = (const float*)d_in[4];
    const float* point_coords = (const float*)d_in[5];
    const int*   tgt_labels   = (const int*)d_in[6];
    float* out = (float*)d_out;

    // workspace layout (16B-aligned), total ~7.6 MB
    char* w = (char*)d_ws;
    int4*           offs  = (int4*)w;                                   // 16 KB
    float4*         wts   = (float4*)(w + 16384);                       // 16 KB
    int*            nearm = (int*)(w + 32768);                          // 4 KB
    unsigned short* tgtPT = (unsigned short*)(w + 36864);               // 256 KB
    unsigned short* xsbuf = (unsigned short*)(w + 36864 + 262144);      // 7.29 MB
    size_t xs_bytes = (size_t)B_*2*QPAD_*P_*2;
    char* w2 = w + 36864 + 262144 + xs_bytes;
    float* tsum = (float*)w2;                    // 512 B
    float* lneg = (float*)(w2 + 512);            // 7200 B (pad to 7296)
    float* lsum = (float*)(w2 + 512 + 7296);     // 7200 B
    float* bmax = (float*)(w2 + 512 + 2*7296);

    k0_meta<<<1, 256, 0, stream>>>(point_coords, offs, wts, nearm, bmax);
    kS_sample<<<B_*T_ + B_*Q_, 256, 0, stream>>>(tgt_masks, pred_masks, offs, wts, nearm,
                                                 tgtPT, tsum, xsbuf, lneg, lsum);
    k3_gemm<<<B_*MT_, 256, 0, stream>>>(xsbuf, tgtPT, lneg, lsum, tsum,
                                        pred_logits, pred_boxes, tgt_boxes, tgt_labels, out, bmax);
    k5_fix<<<(B_*Q_*T_ + 255)/256, 256, 0, stream>>>(out, bmax);
}

// Round 7
// 47.826 us; speedup vs baseline: 1.2699x; 1.2699x over previous
//
#include <hip/hip_runtime.h>
#include <hip/hip_bf16.h>
#include <math.h>

#define B_    2
#define Q_    900
#define QPAD_ 912      // 57 * 16
#define MT_   57
#define CC_   91
#define T_    64
#define H_    128
#define W_    128
#define HW_   (H_*W_)
#define P_    1024
#define FLT_BIG 3.402823466e+38f

typedef short short8 __attribute__((ext_vector_type(8)));   // 8 bf16 (4 VGPRs)
typedef float f32x4  __attribute__((ext_vector_type(4)));

static __device__ __forceinline__ unsigned short f2bf(float v) {
    __hip_bfloat16 h = __float2bfloat16(v);   // RN
    return *reinterpret_cast<unsigned short*>(&h);
}

// ---------------- kS: merged sampler; per-thread tap metadata computed in registers ----------------
// blocks [0, B*T): target nearest-sample; blocks [B*T, B*T+B*Q): pred bilinear-sample
__global__ __launch_bounds__(256) void kS_sample(
    const float* __restrict__ tgt_masks,   // [B,T,H,W]
    const float* __restrict__ pred_masks,  // [B,Q,H,W]
    const float* __restrict__ pc,          // [P,2]
    unsigned short* __restrict__ tgtPT,    // [B][T][P] bf16
    float* __restrict__ tsum,              // [B,T]
    unsigned short* __restrict__ xsbuf,    // [B][2][QPAD][P] bf16 (ch0 = x, ch1 = s)
    float* __restrict__ lneg,              // [B,Q]
    float* __restrict__ lsum,              // [B,Q]
    float* __restrict__ bmax)              // [B] zeroed by block 0 (kS precedes k3's atomics)
{
    const int tid = threadIdx.x;
    const int wv = tid >> 6, lane = tid & 63;
    __shared__ float sSum[2][4];

    if (blockIdx.x < B_*T_) {
        // ---- target role: nearest, grid_sample align_corners=False (rintf == jnp.round) ----
        if (blockIdx.x == 0 && tid < B_) bmax[tid] = 0.f;
        const int bt = blockIdx.x;
        const float* __restrict__ img = tgt_masks + (size_t)bt * HW_;

        float vals[4];
        #pragma unroll
        for (int k = 0; k < 4; ++k) {
            int p = tid*4 + k;
            float px = pc[2*p], py = pc[2*p+1];
            float xf = rintf(px * (float)W_ - 0.5f);
            float yf = rintf(py * (float)H_ - 0.5f);
            bool nv = (xf >= 0.f) && (xf < (float)W_) && (yf >= 0.f) && (yf < (float)H_);
            int xc = (int)fminf(fmaxf(xf, 0.f), (float)(W_-1));
            int yc = (int)fminf(fmaxf(yf, 0.f), (float)(H_-1));
            vals[k] = nv ? img[yc*W_ + xc] : 0.f;
        }
        *(ushort4*)(tgtPT + (size_t)bt*P_ + tid*4) =
            make_ushort4(f2bf(vals[0]), f2bf(vals[1]), f2bf(vals[2]), f2bf(vals[3]));

        float local = (vals[0] + vals[1]) + (vals[2] + vals[3]);
        #pragma unroll
        for (int off = 32; off; off >>= 1) local += __shfl_down(local, off);
        if (lane == 0) sSum[0][wv] = local;
        __syncthreads();
        if (tid == 0) tsum[bt] = (sSum[0][0]+sSum[0][1]) + (sSum[0][2]+sSum[0][3]);
    } else {
        // ---- pred role: bilinear, 4 points/thread, direct gather (no LDS, no staging) ----
        const int bq = blockIdx.x - B_*T_;
        const int b = bq / Q_, q = bq % Q_;
        const float* __restrict__ img = pred_masks + (size_t)bq * HW_;

        // tap metadata in registers
        int   o[4][4];
        float ww[4][4];
        #pragma unroll
        for (int k = 0; k < 4; ++k) {
            int p = tid*4 + k;
            float px = pc[2*p], py = pc[2*p+1];
            float x = px * (float)W_ - 0.5f;
            float y = py * (float)H_ - 0.5f;
            float x0f = floorf(x), y0f = floorf(y);
            float wx1 = x - x0f, wy1 = y - y0f;
            float wx0 = 1.f - wx1, wy0 = 1.f - wy1;
            int x0 = (int)x0f, y0 = (int)y0f;
            int   xs2[2] = {x0, x0+1}, ys2[2] = {y0, y0+1};
            float wxs[2] = {wx0, wx1}, wys[2] = {wy0, wy1};
            #pragma unroll
            for (int dy = 0; dy < 2; ++dy)
            #pragma unroll
            for (int dx = 0; dx < 2; ++dx) {
                int xi = xs2[dx], yi = ys2[dy];
                bool v = (xi >= 0) && (xi < W_) && (yi >= 0) && (yi < H_);
                int xcc = min(max(xi, 0), W_-1);
                int ycc = min(max(yi, 0), H_-1);
                o [k][dy*2+dx] = ycc*W_ + xcc;
                ww[k][dy*2+dx] = v ? wys[dy]*wxs[dx] : 0.f;
            }
        }

        // 16 independent gathers, then combine
        float tap[4][4];
        #pragma unroll
        for (int k = 0; k < 4; ++k) {
            tap[k][0] = img[o[k][0]]; tap[k][1] = img[o[k][1]];
            tap[k][2] = img[o[k][2]]; tap[k][3] = img[o[k][3]];
        }

        float ln = 0.f, ls = 0.f;
        unsigned short px[4], ps[4];
        #pragma unroll
        for (int k = 0; k < 4; ++k) {
            float x = ww[k][0]*tap[k][0] + ww[k][1]*tap[k][1]
                    + ww[k][2]*tap[k][2] + ww[k][3]*tap[k][3];
            float e  = __expf(-fabsf(x));
            float sp = __logf(1.f + e) + fmaxf(x, 0.f);   // softplus(x)
            float r  = 1.f / (1.f + e);
            float s  = (x >= 0.f) ? r : e * r;            // sigmoid(x)
            ln += sp; ls += s;
            px[k] = f2bf(x); ps[k] = f2bf(s);
        }

        *(ushort4*)(xsbuf + ((size_t)(b*2+0)*QPAD_ + q)*P_ + tid*4) = make_ushort4(px[0],px[1],px[2],px[3]);
        *(ushort4*)(xsbuf + ((size_t)(b*2+1)*QPAD_ + q)*P_ + tid*4) = make_ushort4(ps[0],ps[1],ps[2],ps[3]);

        #pragma unroll
        for (int off = 32; off; off >>= 1) {
            ln += __shfl_down(ln, off);
            ls += __shfl_down(ls, off);
        }
        if (lane == 0) { sSum[0][wv] = ln; sSum[1][wv] = ls; }
        __syncthreads();
        if (tid == 0) {
            lneg[b*Q_ + q] = (sSum[0][0]+sSum[0][1]) + (sSum[0][2]+sSum[0][3]);
            lsum[b*Q_ + q] = (sSum[1][0]+sSum[1][1]) + (sSum[1][2]+sSum[1][3]);
        }
    }
}

// ---------------- k3: MFMA GEMM, K split across 4 waves + LDS reduce + fused epilogue + fused max ----------------
__global__ __launch_bounds__(256) void k3_gemm(
    const unsigned short* __restrict__ xsbuf,  // [B][2][QPAD][P] bf16
    const unsigned short* __restrict__ tgtPT,  // [B][T][P] bf16
    const float* __restrict__ lneg,            // [B,Q]
    const float* __restrict__ lsum,            // [B,Q]
    const float* __restrict__ tsum,            // [B,T]
    const float* __restrict__ pred_logits,     // [B,Q,CC]
    const float* __restrict__ pred_boxes,      // [B,Q,4]
    const float* __restrict__ tgt_boxes,       // [B,T,4]
    const int*   __restrict__ tgt_labels,      // [B,T]
    float* __restrict__ out,                   // [B,Q,T]
    float* __restrict__ bmax)                  // [B]
{
    __shared__ f32x4 sAcc[4][64][8];     // 32 KB

    const int bid = blockIdx.x;          // b*MT_ + mt
    const int b = bid / MT_, mt = bid % MT_;
    const int w = threadIdx.x >> 6, l = threadIdx.x & 63;
    const int ml = l & 15, kg = l >> 4;

    // wave w covers k in [w*256, (w+1)*256)
    const short* Ax = (const short*)xsbuf + ((size_t)(b*2+0)*QPAD_ + mt*16 + ml)*P_ + kg*8 + w*256;
    const short* As = (const short*)xsbuf + ((size_t)(b*2+1)*QPAD_ + mt*16 + ml)*P_ + kg*8 + w*256;
    const short* Bb = (const short*)tgtPT + ((size_t)(b*T_) + ml)*P_ + kg*8 + w*256;

    f32x4 accX[4] = {{0,0,0,0},{0,0,0,0},{0,0,0,0},{0,0,0,0}};
    f32x4 accS[4] = {{0,0,0,0},{0,0,0,0},{0,0,0,0},{0,0,0,0}};

    #pragma unroll
    for (int kt = 0; kt < 8; ++kt) {
        const int ko = kt * 32;
        short8 afx = *(const short8*)(Ax + ko);
        short8 afs = *(const short8*)(As + ko);
        #pragma unroll
        for (int nt = 0; nt < 4; ++nt) {
            short8 bf = *(const short8*)(Bb + (size_t)nt*16*P_ + ko);
            accX[nt] = __builtin_amdgcn_mfma_f32_16x16x32_bf16(afx, bf, accX[nt], 0, 0, 0);
            accS[nt] = __builtin_amdgcn_mfma_f32_16x16x32_bf16(afs, bf, accS[nt], 0, 0, 0);
        }
    }

    #pragma unroll
    for (int nt = 0; nt < 4; ++nt) {
        sAcc[w][l][nt*2+0] = accX[nt];
        sAcc[w][l][nt*2+1] = accS[nt];
    }
    __syncthreads();

    // wave w handles epilogue for nt = w (t = w*16 + ml)
    f32x4 aX = sAcc[0][l][w*2+0];
    f32x4 aS = sAcc[0][l][w*2+1];
    #pragma unroll
    for (int w2 = 1; w2 < 4; ++w2) {
        aX += sAcc[w2][l][w*2+0];
        aS += sAcc[w2][l][w*2+1];
    }

    const int t = w*16 + ml;
    const float tsu = tsum[b*T_ + t];
    const int   lab = tgt_labels[b*T_ + t];
    const float4 tbx = *(const float4*)(tgt_boxes + (size_t)(b*T_ + t)*4);
    float tx1 = tbx.x - 0.5f*tbx.z, ty1 = tbx.y - 0.5f*tbx.w;
    float tx2 = tbx.x + 0.5f*tbx.z, ty2 = tbx.y + 0.5f*tbx.w;
    float a2 = (tx2-tx1)*(ty2-ty1);

    float mloc = 0.f;   // per-thread max of where(finite, C, 0) candidates

    #pragma unroll
    for (int r = 0; r < 4; ++r) {
        int q = mt*16 + kg*4 + r;
        int qc = min(q, Q_-1);
        float ln  = lneg[b*Q_ + qc];
        float lsv = lsum[b*Q_ + qc];
        float4 pb = *(const float4*)(pred_boxes + (size_t)(b*Q_ + qc)*4);
        float lg = pred_logits[((size_t)(b*Q_ + qc))*CC_ + lab];

        float ce   = (ln - aX[r]) * (1.f/(float)P_);
        float dice = 1.f - (2.f*aS[r] + 1.f) / (lsv + tsu + 1.f);

        float e  = __expf(-fabsf(lg));
        float lp = log1pf(e);
        float sp_neg = lp + fmaxf(-lg, 0.f);
        float sp_pos = lp + fmaxf( lg, 0.f);
        float prob = 1.f / (1.f + __expf(-lg));
        float cclass = 0.25f*(1.f-prob)*(1.f-prob)*sp_neg - 0.75f*prob*prob*sp_pos;

        float cbbox = fabsf(pb.x-tbx.x) + fabsf(pb.y-tbx.y) + fabsf(pb.z-tbx.z) + fabsf(pb.w-tbx.w);
        float px1 = pb.x - 0.5f*pb.z, py1 = pb.y - 0.5f*pb.w;
        float px2 = pb.x + 0.5f*pb.z, py2 = pb.y + 0.5f*pb.w;
        float a1 = (px2-px1)*(py2-py1);
        float iw = fmaxf(fminf(px2,tx2) - fmaxf(px1,tx1), 0.f);
        float ih = fmaxf(fminf(py2,ty2) - fmaxf(py1,ty1), 0.f);
        float inter = iw*ih;
        float uni = a1 + a2 - inter;
        float iou = inter / uni;
        float cw = fmaxf(fmaxf(px2,tx2) - fminf(px1,tx1), 0.f);
        float ch = fmaxf(fmaxf(py2,ty2) - fminf(py1,ty1), 0.f);
        float ac = cw*ch;
        float giou = iou - (ac - uni)/ac;

        float cost = cbbox + cclass - giou + ce + dice;
        if (q < Q_) {
            out[((size_t)(b*Q_ + q))*T_ + t] = cost;
            float cand = (fabsf(cost) <= FLT_BIG) ? cost : 0.f;
            mloc = fmaxf(mloc, cand);
        }
    }

    // block-reduce max -> one atomic per block (bm >= 0: uint order == float order)
    #pragma unroll
    for (int off = 32; off; off >>= 1) mloc = fmaxf(mloc, __shfl_down(mloc, off));
    __shared__ float sm[4];
    if (l == 0) sm[w] = mloc;
    __syncthreads();
    if (threadIdx.x == 0) {
        float bm = fmaxf(fmaxf(sm[0], sm[1]), fmaxf(sm[2], sm[3]));
        atomicMax((unsigned int*)&bmax[b], __float_as_uint(bm));
    }
}

// ---------------- k5: replace non-finite with 2*max ----------------
__global__ __launch_bounds__(256) void k5_fix(float* __restrict__ out,
                                              const float* __restrict__ bmax)
{
    int i = blockIdx.x*256 + threadIdx.x;
    if (i >= B_*Q_*T_) return;
    float v = out[i];
    if (!(fabsf(v) <= FLT_BIG))
        out[i] = 2.f * bmax[i / (Q_*T_)];
}

extern "C" void kernel_launch(void* const* d_in, const int* in_sizes, int n_in,
                              void* d_out, int out_size, void* d_ws, size_t ws_size,
                              hipStream_t stream) {
    const float* pred_logits  = (const float*)d_in[0];
    const float* pred_boxes   = (const float*)d_in[1];
    const float* pred_masks   = (const float*)d_in[2];
    const float* tgt_boxes    = (const float*)d_in[3];
    const float* tgt_masks    = (const float*)d_in[4];
    const float* point_coords = (const float*)d_in[5];
    const int*   tgt_labels   = (const int*)d_in[6];
    float* out = (float*)d_out;

    // workspace layout (16B-aligned), total ~7.6 MB
    char* w = (char*)d_ws;
    unsigned short* tgtPT = (unsigned short*)w;                    // 256 KB
    unsigned short* xsbuf = (unsigned short*)(w + 262144);         // 7.29 MB
    size_t xs_bytes = (size_t)B_*2*QPAD_*P_*2;
    char* w2 = w + 262144 + xs_bytes;
    float* tsum = (float*)w2;                    // 512 B
    float* lneg = (float*)(w2 + 512);            // 7200 B (pad to 7296)
    float* lsum = (float*)(w2 + 512 + 7296);     // 7200 B
    float* bmax = (float*)(w2 + 512 + 2*7296);

    kS_sample<<<B_*T_ + B_*Q_, 256, 0, stream>>>(tgt_masks, pred_masks, point_coords,
                                                 tgtPT, tsum, xsbuf, lneg, lsum, bmax);
    k3_gemm<<<B_*MT_, 256, 0, stream>>>(xsbuf, tgtPT, lneg, lsum, tsum,
                                        pred_logits, pred_boxes, tgt_boxes, tgt_labels, out, bmax);
    k5_fix<<<(B_*Q_*T_ + 255)/256, 256, 0, stream>>>(out, bmax);
}

// Round 8
// 47.630 us; speedup vs baseline: 1.2751x; 1.0041x over previous
//
#include <hip/hip_runtime.h>
#include <hip/hip_bf16.h>
#include <math.h>

#define B_    2
#define Q_    900
#define QPAD_ 912      // 57 * 16
#define MT_   57
#define CC_   91
#define T_    64
#define H_    128
#define W_    128
#define HW_   (H_*W_)
#define P_    1024
#define FLT_BIG 3.402823466e+38f

typedef short short8 __attribute__((ext_vector_type(8)));   // 8 bf16 (4 VGPRs)
typedef float f32x4  __attribute__((ext_vector_type(4)));

static __device__ __forceinline__ unsigned short f2bf(float v) {
    __hip_bfloat16 h = __float2bfloat16(v);   // RN
    return *reinterpret_cast<unsigned short*>(&h);
}

// ---------------- kS: merged sampler; pair-load gathers (8 loads/thread) ----------------
// blocks [0, B*T): target nearest-sample; blocks [B*T, B*T+B*Q): pred bilinear-sample
__global__ __launch_bounds__(256) void kS_sample(
    const float* __restrict__ tgt_masks,   // [B,T,H,W]
    const float* __restrict__ pred_masks,  // [B,Q,H,W]
    const float* __restrict__ pc,          // [P,2]
    unsigned short* __restrict__ tgtPT,    // [B][T][P] bf16
    float* __restrict__ tsum,              // [B,T]
    unsigned short* __restrict__ xsbuf,    // [B][2][QPAD][P] bf16 (ch0 = x, ch1 = s)
    float* __restrict__ lneg,              // [B,Q]
    float* __restrict__ lsum,              // [B,Q]
    float* __restrict__ bmax)              // [B] zeroed by block 0 (kS precedes k3's atomics)
{
    const int tid = threadIdx.x;
    const int wv = tid >> 6, lane = tid & 63;
    __shared__ float sSum[2][4];

    if (blockIdx.x < B_*T_) {
        // ---- target role: nearest, grid_sample align_corners=False (rintf == jnp.round) ----
        if (blockIdx.x == 0 && tid < B_) bmax[tid] = 0.f;
        const int bt = blockIdx.x;
        const float* __restrict__ img = tgt_masks + (size_t)bt * HW_;

        float vals[4];
        #pragma unroll
        for (int k = 0; k < 4; ++k) {
            int p = tid*4 + k;
            float px = pc[2*p], py = pc[2*p+1];
            float xf = rintf(px * (float)W_ - 0.5f);
            float yf = rintf(py * (float)H_ - 0.5f);
            bool nv = (xf >= 0.f) && (xf < (float)W_) && (yf >= 0.f) && (yf < (float)H_);
            int xc = (int)fminf(fmaxf(xf, 0.f), (float)(W_-1));
            int yc = (int)fminf(fmaxf(yf, 0.f), (float)(H_-1));
            vals[k] = nv ? img[yc*W_ + xc] : 0.f;
        }
        *(ushort4*)(tgtPT + (size_t)bt*P_ + tid*4) =
            make_ushort4(f2bf(vals[0]), f2bf(vals[1]), f2bf(vals[2]), f2bf(vals[3]));

        float local = (vals[0] + vals[1]) + (vals[2] + vals[3]);
        #pragma unroll
        for (int off = 32; off; off >>= 1) local += __shfl_down(local, off);
        if (lane == 0) sSum[0][wv] = local;
        __syncthreads();
        if (tid == 0) tsum[bt] = (sSum[0][0]+sSum[0][1]) + (sSum[0][2]+sSum[0][3]);
    } else {
        // ---- pred role: bilinear via row-pair loads; 4 points/thread, 8 gather instrs ----
        const int bq = blockIdx.x - B_*T_;
        const int b = bq / Q_, q = bq % Q_;
        const float* __restrict__ img = pred_masks + (size_t)bq * HW_;

        // metadata in registers: pair base addrs + remapped pair weights
        int   base0[4], base1[4];
        float wp0[4], wp1[4], wyv0[4], wyv1[4];
        #pragma unroll
        for (int k = 0; k < 4; ++k) {
            int p = tid*4 + k;
            float px = pc[2*p], py = pc[2*p+1];
            float xf = px * (float)W_ - 0.5f;
            float yf = py * (float)H_ - 0.5f;
            float x0f = floorf(xf), y0f = floorf(yf);
            float wx1 = xf - x0f, wx0 = 1.f - wx1;
            float wy1 = yf - y0f, wy0 = 1.f - wy1;
            int x0 = (int)x0f, y0 = (int)y0f;
            // pair covers (xa, xa+1); remap tap weights onto pair slots (coords in [-1,W-1])
            int xa = min(max(x0, 0), W_-2);
            wp0[k] = (x0 == xa) ? wx0 : ((x0 < xa) ? wx1 : 0.f);  // x0=-1 -> (wx1,0)
            wp1[k] = (x0 == xa) ? wx1 : ((x0 > xa) ? wx0 : 0.f);  // x0=W-1 -> (0,wx0)
            wyv0[k] = (y0 >= 0 && y0 < H_)       ? wy0 : 0.f;
            wyv1[k] = (y0+1 >= 0 && y0+1 < H_)   ? wy1 : 0.f;
            int ya0 = min(max(y0,   0), H_-1);
            int ya1 = min(max(y0+1, 0), H_-1);
            base0[k] = ya0*W_ + xa;
            base1[k] = ya1*W_ + xa;
        }

        // 8 independent pair-gathers (unaligned-safe via memcpy -> dwordx2)
        float2 r0[4], r1[4];
        #pragma unroll
        for (int k = 0; k < 4; ++k) {
            __builtin_memcpy(&r0[k], img + base0[k], 8);
            __builtin_memcpy(&r1[k], img + base1[k], 8);
        }

        float ln = 0.f, ls = 0.f;
        unsigned short px_[4], ps_[4];
        #pragma unroll
        for (int k = 0; k < 4; ++k) {
            float x = wyv0[k]*(wp0[k]*r0[k].x + wp1[k]*r0[k].y)
                    + wyv1[k]*(wp0[k]*r1[k].x + wp1[k]*r1[k].y);
            float e  = __expf(-fabsf(x));
            float sp = __logf(1.f + e) + fmaxf(x, 0.f);   // softplus(x)
            float rr = 1.f / (1.f + e);
            float s  = (x >= 0.f) ? rr : e * rr;          // sigmoid(x)
            ln += sp; ls += s;
            px_[k] = f2bf(x); ps_[k] = f2bf(s);
        }

        *(ushort4*)(xsbuf + ((size_t)(b*2+0)*QPAD_ + q)*P_ + tid*4) = make_ushort4(px_[0],px_[1],px_[2],px_[3]);
        *(ushort4*)(xsbuf + ((size_t)(b*2+1)*QPAD_ + q)*P_ + tid*4) = make_ushort4(ps_[0],ps_[1],ps_[2],ps_[3]);

        #pragma unroll
        for (int off = 32; off; off >>= 1) {
            ln += __shfl_down(ln, off);
            ls += __shfl_down(ls, off);
        }
        if (lane == 0) { sSum[0][wv] = ln; sSum[1][wv] = ls; }
        __syncthreads();
        if (tid == 0) {
            lneg[b*Q_ + q] = (sSum[0][0]+sSum[0][1]) + (sSum[0][2]+sSum[0][3]);
            lsum[b*Q_ + q] = (sSum[1][0]+sSum[1][1]) + (sSum[1][2]+sSum[1][3]);
        }
    }
}

// ---------------- k3: MFMA GEMM, 456 blocks (b,mt,nt), 4-wave K-split, parallel epilogue ----------------
__global__ __launch_bounds__(256) void k3_gemm(
    const unsigned short* __restrict__ xsbuf,  // [B][2][QPAD][P] bf16
    const unsigned short* __restrict__ tgtPT,  // [B][T][P] bf16
    const float* __restrict__ lneg,            // [B,Q]
    const float* __restrict__ lsum,            // [B,Q]
    const float* __restrict__ tsum,            // [B,T]
    const float* __restrict__ pred_logits,     // [B,Q,CC]
    const float* __restrict__ pred_boxes,      // [B,Q,4]
    const float* __restrict__ tgt_boxes,       // [B,T,4]
    const int*   __restrict__ tgt_labels,      // [B,T]
    float* __restrict__ out,                   // [B,Q,T]
    float* __restrict__ bmax)                  // [B]
{
    __shared__ float sT[2][4][4][65];    // [ch][reg][wave][lane(+1 pad)] ~8.3 KB

    const int bid = blockIdx.x;          // b*(MT_*4) + mt*4 + nt
    const int b = bid / (MT_*4);
    const int rem = bid % (MT_*4);
    const int mt = rem >> 2, nt = rem & 3;
    const int w = threadIdx.x >> 6, l = threadIdx.x & 63;
    const int ml = l & 15, kg = l >> 4;

    // wave w covers k in [w*256, (w+1)*256); A: m=l&15,k=(l>>4)*8+j; B: n=l&15,k=(l>>4)*8+j
    const short* Ax = (const short*)xsbuf + ((size_t)(b*2+0)*QPAD_ + mt*16 + ml)*P_ + kg*8 + w*256;
    const short* As = (const short*)xsbuf + ((size_t)(b*2+1)*QPAD_ + mt*16 + ml)*P_ + kg*8 + w*256;
    const short* Bb = (const short*)tgtPT + ((size_t)(b*T_) + nt*16 + ml)*P_ + kg*8 + w*256;

    f32x4 accX = {0,0,0,0};
    f32x4 accS = {0,0,0,0};

    #pragma unroll
    for (int kt = 0; kt < 8; ++kt) {
        const int ko = kt * 32;
        short8 afx = *(const short8*)(Ax + ko);
        short8 afs = *(const short8*)(As + ko);
        short8 bf  = *(const short8*)(Bb + ko);
        accX = __builtin_amdgcn_mfma_f32_16x16x32_bf16(afx, bf, accX, 0, 0, 0);
        accS = __builtin_amdgcn_mfma_f32_16x16x32_bf16(afs, bf, accS, 0, 0, 0);
    }

    // C layout: lane l holds col=l&15, rows kg*4+r
    #pragma unroll
    for (int r = 0; r < 4; ++r) {
        sT[0][r][w][l] = accX[r];
        sT[1][r][w][l] = accS[r];
    }
    __syncthreads();

    // epilogue: one (q,t) per thread. tid -> q_local = tid>>4, t_local = tid&15
    const int tid = threadIdx.x;
    const int ql = tid >> 4, tc = tid & 15;
    const int r   = ql & 3;
    const int src = (ql >> 2)*16 + tc;   // source lane = kg*16 + col

    float aX = ((sT[0][r][0][src] + sT[0][r][1][src]) + (sT[0][r][2][src] + sT[0][r][3][src]));
    float aS = ((sT[1][r][0][src] + sT[1][r][1][src]) + (sT[1][r][2][src] + sT[1][r][3][src]));

    const int q = mt*16 + ql;
    const int t = nt*16 + tc;
    const int qc = min(q, Q_-1);

    const float tsu = tsum[b*T_ + t];
    const int   lab = tgt_labels[b*T_ + t];
    const float4 tbx = *(const float4*)(tgt_boxes + (size_t)(b*T_ + t)*4);
    float ln  = lneg[b*Q_ + qc];
    float lsv = lsum[b*Q_ + qc];
    float4 pb = *(const float4*)(pred_boxes + (size_t)(b*Q_ + qc)*4);
    float lg  = pred_logits[((size_t)(b*Q_ + qc))*CC_ + lab];

    float ce   = (ln - aX) * (1.f/(float)P_);
    float dice = 1.f - (2.f*aS + 1.f) / (lsv + tsu + 1.f);

    float e  = __expf(-fabsf(lg));
    float lp = log1pf(e);
    float sp_neg = lp + fmaxf(-lg, 0.f);
    float sp_pos = lp + fmaxf( lg, 0.f);
    float prob = 1.f / (1.f + __expf(-lg));
    float cclass = 0.25f*(1.f-prob)*(1.f-prob)*sp_neg - 0.75f*prob*prob*sp_pos;

    float cbbox = fabsf(pb.x-tbx.x) + fabsf(pb.y-tbx.y) + fabsf(pb.z-tbx.z) + fabsf(pb.w-tbx.w);
    float px1 = pb.x - 0.5f*pb.z, py1 = pb.y - 0.5f*pb.w;
    float px2 = pb.x + 0.5f*pb.z, py2 = pb.y + 0.5f*pb.w;
    float tx1 = tbx.x - 0.5f*tbx.z, ty1 = tbx.y - 0.5f*tbx.w;
    float tx2 = tbx.x + 0.5f*tbx.z, ty2 = tbx.y + 0.5f*tbx.w;
    float a1 = (px2-px1)*(py2-py1);
    float a2 = (tx2-tx1)*(ty2-ty1);
    float iw = fmaxf(fminf(px2,tx2) - fmaxf(px1,tx1), 0.f);
    float ih = fmaxf(fminf(py2,ty2) - fmaxf(py1,ty1), 0.f);
    float inter = iw*ih;
    float uni = a1 + a2 - inter;
    float iou = inter / uni;
    float cw = fmaxf(fmaxf(px2,tx2) - fminf(px1,tx1), 0.f);
    float ch = fmaxf(fmaxf(py2,ty2) - fminf(py1,ty1), 0.f);
    float ac = cw*ch;
    float giou = iou - (ac - uni)/ac;

    float cost = cbbox + cclass - giou + ce + dice;
    float mloc = 0.f;
    if (q < Q_) {
        out[((size_t)(b*Q_ + q))*T_ + t] = cost;
        mloc = (fabsf(cost) <= FLT_BIG) ? fmaxf(cost, 0.f) : 0.f;
    }

    // block-reduce max -> one atomic per block (candidates >= 0: uint order == float order)
    #pragma unroll
    for (int off = 32; off; off >>= 1) mloc = fmaxf(mloc, __shfl_down(mloc, off));
    __shared__ float sm[4];
    if (l == 0) sm[w] = mloc;
    __syncthreads();
    if (tid == 0) {
        float bm = fmaxf(fmaxf(sm[0], sm[1]), fmaxf(sm[2], sm[3]));
        atomicMax((unsigned int*)&bmax[b], __float_as_uint(bm));
    }
}

// ---------------- k5: replace non-finite with 2*max ----------------
__global__ __launch_bounds__(256) void k5_fix(float* __restrict__ out,
                                              const float* __restrict__ bmax)
{
    int i = blockIdx.x*256 + threadIdx.x;
    if (i >= B_*Q_*T_) return;
    float v = out[i];
    if (!(fabsf(v) <= FLT_BIG))
        out[i] = 2.f * bmax[i / (Q_*T_)];
}

extern "C" void kernel_launch(void* const* d_in, const int* in_sizes, int n_in,
                              void* d_out, int out_size, void* d_ws, size_t ws_size,
                              hipStream_t stream) {
    const float* pred_logits  = (const float*)d_in[0];
    const float* pred_boxes   = (const float*)d_in[1];
    const float* pred_masks   = (const float*)d_in[2];
    const float* tgt_boxes    = (const float*)d_in[3];
    const float* tgt_masks    = (const float*)d_in[4];
    const float* point_coords = (const float*)d_in[5];
    const int*   tgt_labels   = (const int*)d_in[6];
    float* out = (float*)d_out;

    // workspace layout (16B-aligned), total ~7.6 MB
    char* w = (char*)d_ws;
    unsigned short* tgtPT = (unsigned short*)w;                    // 256 KB
    unsigned short* xsbuf = (unsigned short*)(w + 262144);         // 7.29 MB
    size_t xs_bytes = (size_t)B_*2*QPAD_*P_*2;
    char* w2 = w + 262144 + xs_bytes;
    float* tsum = (float*)w2;                    // 512 B
    float* lneg = (float*)(w2 + 512);            // 7200 B (pad to 7296)
    float* lsum = (float*)(w2 + 512 + 7296);     // 7200 B
    float* bmax = (float*)(w2 + 512 + 2*7296);

    kS_sample<<<B_*T_ + B_*Q_, 256, 0, stream>>>(tgt_masks, pred_masks, point_coords,
                                                 tgtPT, tsum, xsbuf, lneg, lsum, bmax);
    k3_gemm<<<B_*MT_*4, 256, 0, stream>>>(xsbuf, tgtPT, lneg, lsum, tsum,
                                          pred_logits, pred_boxes, tgt_boxes, tgt_labels, out, bmax);
    k5_fix<<<(B_*Q_*T_ + 255)/256, 256, 0, stream>>>(out, bmax);
}

// Round 9
// 39.343 us; speedup vs baseline: 1.5437x; 1.2106x over previous
//
#include <hip/hip_runtime.h>
#include <hip/hip_bf16.h>
#include <math.h>

#define B_    2
#define Q_    900
#define QPAD_ 912      // 57 * 16
#define MT_   57
#define CC_   91
#define T_    64
#define H_    128
#define W_    128
#define HW_   (H_*W_)
#define P_    1024
#define FLT_BIG 3.402823466e+38f

#define AS1 __attribute__((address_space(1)))
#define AS3 __attribute__((address_space(3)))

typedef short short8 __attribute__((ext_vector_type(8)));   // 8 bf16 (4 VGPRs)
typedef float f32x4  __attribute__((ext_vector_type(4)));

static __device__ __forceinline__ unsigned short f2bf(float v) {
    __hip_bfloat16 h = __float2bfloat16(v);   // RN
    return *reinterpret_cast<unsigned short*>(&h);
}

// ---------------- kS: merged sampler; streaming DMA stage -> LDS gather ----------------
// blocks [0, B*T): target nearest-sample; blocks [B*T, B*T+B*Q): pred bilinear-sample
__global__ __launch_bounds__(256) void kS_sample(
    const float* __restrict__ tgt_masks,   // [B,T,H,W]
    const float* __restrict__ pred_masks,  // [B,Q,H,W]
    const float* __restrict__ pc,          // [P,2]
    unsigned short* __restrict__ tgtPT,    // [B][T][P] bf16
    float* __restrict__ tsum,              // [B,T]
    unsigned short* __restrict__ xsbuf,    // [B][2][QPAD][P] bf16 (ch0 = x, ch1 = s)
    float* __restrict__ lneg,              // [B,Q]
    float* __restrict__ lsum,              // [B,Q]
    float* __restrict__ bmax)              // [B] zeroed by block 0 (kS precedes k3's atomics)
{
    __shared__ float simg[HW_];            // 64 KB staged image
    __shared__ float sSum[2][4];

    const int tid = threadIdx.x;
    const int wv = tid >> 6, lane = tid & 63;
    const bool isTgt = (blockIdx.x < (B_*T_));
    const float* __restrict__ img = isTgt
        ? (tgt_masks  + (size_t)blockIdx.x * HW_)
        : (pred_masks + (size_t)(blockIdx.x - B_*T_) * HW_);

    // ---- streaming global->LDS DMA (issue first; VALU metadata overlaps latency) ----
    // wave wv copies 16 chunks of 1 KB: 64 lanes x 16 B, linear LDS dest (m97 pattern)
    {
        const float* gbase = img  + wv*4096 + lane*4;
        float*       lbase = simg + wv*4096;
        #pragma unroll
        for (int it = 0; it < 16; ++it) {
            __builtin_amdgcn_global_load_lds((const AS1 float*)(gbase + it*256),
                                             (AS3 float*)(lbase + it*256),
                                             16, 0, 0);
        }
    }

    if (isTgt) {
        // ---- target role: nearest, grid_sample align_corners=False (rintf == jnp.round) ----
        if (blockIdx.x == 0 && tid < B_) bmax[tid] = 0.f;
        const int bt = blockIdx.x;

        int   nidx[4];
        #pragma unroll
        for (int k = 0; k < 4; ++k) {
            int p = tid*4 + k;
            float px = pc[2*p], py = pc[2*p+1];
            float xf = rintf(px * (float)W_ - 0.5f);
            float yf = rintf(py * (float)H_ - 0.5f);
            bool nv = (xf >= 0.f) && (xf < (float)W_) && (yf >= 0.f) && (yf < (float)H_);
            int xc = (int)fminf(fmaxf(xf, 0.f), (float)(W_-1));
            int yc = (int)fminf(fmaxf(yf, 0.f), (float)(H_-1));
            nidx[k] = nv ? (yc*W_ + xc) : -1;
        }
        __syncthreads();   // DMA drained (vmcnt(0) before barrier)

        float vals[4];
        #pragma unroll
        for (int k = 0; k < 4; ++k)
            vals[k] = (nidx[k] >= 0) ? simg[nidx[k]] : 0.f;

        *(ushort4*)(tgtPT + (size_t)bt*P_ + tid*4) =
            make_ushort4(f2bf(vals[0]), f2bf(vals[1]), f2bf(vals[2]), f2bf(vals[3]));

        float local = (vals[0] + vals[1]) + (vals[2] + vals[3]);
        #pragma unroll
        for (int off = 32; off; off >>= 1) local += __shfl_down(local, off);
        if (lane == 0) sSum[0][wv] = local;
        __syncthreads();
        if (tid == 0) tsum[bt] = (sSum[0][0]+sSum[0][1]) + (sSum[0][2]+sSum[0][3]);
    } else {
        // ---- pred role: bilinear, 4 points/thread, gather from LDS ----
        const int bq = blockIdx.x - B_*T_;
        const int b = bq / Q_, q = bq % Q_;

        // tap metadata in registers (overlaps DMA)
        int   o[4][4];
        float ww[4][4];
        #pragma unroll
        for (int k = 0; k < 4; ++k) {
            int p = tid*4 + k;
            float px = pc[2*p], py = pc[2*p+1];
            float x = px * (float)W_ - 0.5f;
            float y = py * (float)H_ - 0.5f;
            float x0f = floorf(x), y0f = floorf(y);
            float wx1 = x - x0f, wy1 = y - y0f;
            float wx0 = 1.f - wx1, wy0 = 1.f - wy1;
            int x0 = (int)x0f, y0 = (int)y0f;
            int   xs2[2] = {x0, x0+1}, ys2[2] = {y0, y0+1};
            float wxs[2] = {wx0, wx1}, wys[2] = {wy0, wy1};
            #pragma unroll
            for (int dy = 0; dy < 2; ++dy)
            #pragma unroll
            for (int dx = 0; dx < 2; ++dx) {
                int xi = xs2[dx], yi = ys2[dy];
                bool v = (xi >= 0) && (xi < W_) && (yi >= 0) && (yi < H_);
                int xcc = min(max(xi, 0), W_-1);
                int ycc = min(max(yi, 0), H_-1);
                o [k][dy*2+dx] = ycc*W_ + xcc;
                ww[k][dy*2+dx] = v ? wys[dy]*wxs[dx] : 0.f;
            }
        }
        __syncthreads();   // DMA drained

        float tap[4][4];
        #pragma unroll
        for (int k = 0; k < 4; ++k) {
            tap[k][0] = simg[o[k][0]]; tap[k][1] = simg[o[k][1]];
            tap[k][2] = simg[o[k][2]]; tap[k][3] = simg[o[k][3]];
        }

        float ln = 0.f, ls = 0.f;
        unsigned short px_[4], ps_[4];
        #pragma unroll
        for (int k = 0; k < 4; ++k) {
            float x = ww[k][0]*tap[k][0] + ww[k][1]*tap[k][1]
                    + ww[k][2]*tap[k][2] + ww[k][3]*tap[k][3];
            float e  = __expf(-fabsf(x));
            float sp = __logf(1.f + e) + fmaxf(x, 0.f);   // softplus(x)
            float rr = 1.f / (1.f + e);
            float s  = (x >= 0.f) ? rr : e * rr;          // sigmoid(x)
            ln += sp; ls += s;
            px_[k] = f2bf(x); ps_[k] = f2bf(s);
        }

        *(ushort4*)(xsbuf + ((size_t)(b*2+0)*QPAD_ + q)*P_ + tid*4) = make_ushort4(px_[0],px_[1],px_[2],px_[3]);
        *(ushort4*)(xsbuf + ((size_t)(b*2+1)*QPAD_ + q)*P_ + tid*4) = make_ushort4(ps_[0],ps_[1],ps_[2],ps_[3]);

        #pragma unroll
        for (int off = 32; off; off >>= 1) {
            ln += __shfl_down(ln, off);
            ls += __shfl_down(ls, off);
        }
        if (lane == 0) { sSum[0][wv] = ln; sSum[1][wv] = ls; }
        __syncthreads();
        if (tid == 0) {
            lneg[b*Q_ + q] = (sSum[0][0]+sSum[0][1]) + (sSum[0][2]+sSum[0][3]);
            lsum[b*Q_ + q] = (sSum[1][0]+sSum[1][1]) + (sSum[1][2]+sSum[1][3]);
        }
    }
}

// ---------------- k3: MFMA GEMM, 456 blocks (b,mt,nt), 4-wave K-split, parallel epilogue ----------------
__global__ __launch_bounds__(256) void k3_gemm(
    const unsigned short* __restrict__ xsbuf,  // [B][2][QPAD][P] bf16
    const unsigned short* __restrict__ tgtPT,  // [B][T][P] bf16
    const float* __restrict__ lneg,            // [B,Q]
    const float* __restrict__ lsum,            // [B,Q]
    const float* __restrict__ tsum,            // [B,T]
    const float* __restrict__ pred_logits,     // [B,Q,CC]
    const float* __restrict__ pred_boxes,      // [B,Q,4]
    const float* __restrict__ tgt_boxes,       // [B,T,4]
    const int*   __restrict__ tgt_labels,      // [B,T]
    float* __restrict__ out,                   // [B,Q,T]
    float* __restrict__ bmax)                  // [B]
{
    __shared__ float sT[2][4][4][65];    // [ch][reg][wave][lane(+1 pad)] ~8.3 KB

    const int bid = blockIdx.x;          // b*(MT_*4) + mt*4 + nt
    const int b = bid / (MT_*4);
    const int rem = bid % (MT_*4);
    const int mt = rem >> 2, nt = rem & 3;
    const int w = threadIdx.x >> 6, l = threadIdx.x & 63;
    const int ml = l & 15, kg = l >> 4;

    // wave w covers k in [w*256, (w+1)*256); A: m=l&15,k=(l>>4)*8+j; B: n=l&15,k=(l>>4)*8+j
    const short* Ax = (const short*)xsbuf + ((size_t)(b*2+0)*QPAD_ + mt*16 + ml)*P_ + kg*8 + w*256;
    const short* As = (const short*)xsbuf + ((size_t)(b*2+1)*QPAD_ + mt*16 + ml)*P_ + kg*8 + w*256;
    const short* Bb = (const short*)tgtPT + ((size_t)(b*T_) + nt*16 + ml)*P_ + kg*8 + w*256;

    f32x4 accX = {0,0,0,0};
    f32x4 accS = {0,0,0,0};

    #pragma unroll
    for (int kt = 0; kt < 8; ++kt) {
        const int ko = kt * 32;
        short8 afx = *(const short8*)(Ax + ko);
        short8 afs = *(const short8*)(As + ko);
        short8 bf  = *(const short8*)(Bb + ko);
        accX = __builtin_amdgcn_mfma_f32_16x16x32_bf16(afx, bf, accX, 0, 0, 0);
        accS = __builtin_amdgcn_mfma_f32_16x16x32_bf16(afs, bf, accS, 0, 0, 0);
    }

    // C layout: lane l holds col=l&15, rows kg*4+r
    #pragma unroll
    for (int r = 0; r < 4; ++r) {
        sT[0][r][w][l] = accX[r];
        sT[1][r][w][l] = accS[r];
    }
    __syncthreads();

    // epilogue: one (q,t) per thread. tid -> q_local = tid>>4, t_local = tid&15
    const int tid = threadIdx.x;
    const int ql = tid >> 4, tc = tid & 15;
    const int r   = ql & 3;
    const int src = (ql >> 2)*16 + tc;   // source lane = kg*16 + col

    float aX = ((sT[0][r][0][src] + sT[0][r][1][src]) + (sT[0][r][2][src] + sT[0][r][3][src]));
    float aS = ((sT[1][r][0][src] + sT[1][r][1][src]) + (sT[1][r][2][src] + sT[1][r][3][src]));

    const int q = mt*16 + ql;
    const int t = nt*16 + tc;
    const int qc = min(q, Q_-1);

    const float tsu = tsum[b*T_ + t];
    const int   lab = tgt_labels[b*T_ + t];
    const float4 tbx = *(const float4*)(tgt_boxes + (size_t)(b*T_ + t)*4);
    float ln  = lneg[b*Q_ + qc];
    float lsv = lsum[b*Q_ + qc];
    float4 pb = *(const float4*)(pred_boxes + (size_t)(b*Q_ + qc)*4);
    float lg  = pred_logits[((size_t)(b*Q_ + qc))*CC_ + lab];

    float ce   = (ln - aX) * (1.f/(float)P_);
    float dice = 1.f - (2.f*aS + 1.f) / (lsv + tsu + 1.f);

    float e  = __expf(-fabsf(lg));
    float lp = log1pf(e);
    float sp_neg = lp + fmaxf(-lg, 0.f);
    float sp_pos = lp + fmaxf( lg, 0.f);
    float prob = 1.f / (1.f + __expf(-lg));
    float cclass = 0.25f*(1.f-prob)*(1.f-prob)*sp_neg - 0.75f*prob*prob*sp_pos;

    float cbbox = fabsf(pb.x-tbx.x) + fabsf(pb.y-tbx.y) + fabsf(pb.z-tbx.z) + fabsf(pb.w-tbx.w);
    float px1 = pb.x - 0.5f*pb.z, py1 = pb.y - 0.5f*pb.w;
    float px2 = pb.x + 0.5f*pb.z, py2 = pb.y + 0.5f*pb.w;
    float tx1 = tbx.x - 0.5f*tbx.z, ty1 = tbx.y - 0.5f*tbx.w;
    float tx2 = tbx.x + 0.5f*tbx.z, ty2 = tbx.y + 0.5f*tbx.w;
    float a1 = (px2-px1)*(py2-py1);
    float a2 = (tx2-tx1)*(ty2-ty1);
    float iw = fmaxf(fminf(px2,tx2) - fmaxf(px1,tx1), 0.f);
    float ih = fmaxf(fminf(py2,ty2) - fmaxf(py1,ty1), 0.f);
    float inter = iw*ih;
    float uni = a1 + a2 - inter;
    float iou = inter / uni;
    float cw = fmaxf(fmaxf(px2,tx2) - fminf(px1,tx1), 0.f);
    float ch = fmaxf(fmaxf(py2,ty2) - fminf(py1,ty1), 0.f);
    float ac = cw*ch;
    float giou = iou - (ac - uni)/ac;

    float cost = cbbox + cclass - giou + ce + dice;
    float mloc = 0.f;
    if (q < Q_) {
        out[((size_t)(b*Q_ + q))*T_ + t] = cost;
        mloc = (fabsf(cost) <= FLT_BIG) ? fmaxf(cost, 0.f) : 0.f;
    }

    // block-reduce max -> one atomic per block (candidates >= 0: uint order == float order)
    #pragma unroll
    for (int off = 32; off; off >>= 1) mloc = fmaxf(mloc, __shfl_down(mloc, off));
    __shared__ float sm[4];
    if (l == 0) sm[w] = mloc;
    __syncthreads();
    if (tid == 0) {
        float bm = fmaxf(fmaxf(sm[0], sm[1]), fmaxf(sm[2], sm[3]));
        atomicMax((unsigned int*)&bmax[b], __float_as_uint(bm));
    }
}

// ---------------- k5: replace non-finite with 2*max ----------------
__global__ __launch_bounds__(256) void k5_fix(float* __restrict__ out,
                                              const float* __restrict__ bmax)
{
    int i = blockIdx.x*256 + threadIdx.x;
    if (i >= B_*Q_*T_) return;
    float v = out[i];
    if (!(fabsf(v) <= FLT_BIG))
        out[i] = 2.f * bmax[i / (Q_*T_)];
}

extern "C" void kernel_launch(void* const* d_in, const int* in_sizes, int n_in,
                              void* d_out, int out_size, void* d_ws, size_t ws_size,
                              hipStream_t stream) {
    const float* pred_logits  = (const float*)d_in[0];
    const float* pred_boxes   = (const float*)d_in[1];
    const float* pred_masks   = (const float*)d_in[2];
    const float* tgt_boxes    = (const float*)d_in[3];
    const float* tgt_masks    = (const float*)d_in[4];
    const float* point_coords = (const float*)d_in[5];
    const int*   tgt_labels   = (const int*)d_in[6];
    float* out = (float*)d_out;

    // workspace layout (16B-aligned), total ~7.6 MB
    char* w = (char*)d_ws;
    unsigned short* tgtPT = (unsigned short*)w;                    // 256 KB
    unsigned short* xsbuf = (unsigned short*)(w + 262144);         // 7.29 MB
    size_t xs_bytes = (size_t)B_*2*QPAD_*P_*2;
    char* w2 = w + 262144 + xs_bytes;
    float* tsum = (float*)w2;                    // 512 B
    float* lneg = (float*)(w2 + 512);            // 7200 B (pad to 7296)
    float* lsum = (float*)(w2 + 512 + 7296);     // 7200 B
    float* bmax = (float*)(w2 + 512 + 2*7296);

    kS_sample<<<B_*T_ + B_*Q_, 256, 0, stream>>>(tgt_masks, pred_masks, point_coords,
                                                 tgtPT, tsum, xsbuf, lneg, lsum, bmax);
    k3_gemm<<<B_*MT_*4, 256, 0, stream>>>(xsbuf, tgtPT, lneg, lsum, tsum,
                                          pred_logits, pred_boxes, tgt_boxes, tgt_labels, out, bmax);
    k5_fix<<<(B_*Q_*T_ + 255)/256, 256, 0, stream>>>(out, bmax);
}